// Round 1
// baseline (61.572 us; speedup 1.0000x reference)
//
#include <hip/hip_runtime.h>
#include <math.h>

#define NUM_Q 64
#define NUM_P 1024
#define BLOCK 256
#define PER_THREAD (NUM_P / BLOCK)   // 4

// One block per query. loss[q] = sum_{j:rel} sum_{k:!rel} relu(pred[k]-pred[j])
__global__ __launch_bounds__(BLOCK) void per_query_loss_kernel(
    const float* __restrict__ pred,
    const float* __restrict__ y,
    float* __restrict__ partial)   // [NUM_Q]
{
    __shared__ float relVals[NUM_P];
    __shared__ int   relCount;
    __shared__ float waveSums[BLOCK / 64];

    const int q   = blockIdx.x;
    const int tid = threadIdx.x;
    const float* __restrict__ prow = pred + q * NUM_P;
    const float* __restrict__ yrow = y    + q * NUM_P;

    if (tid == 0) relCount = 0;
    __syncthreads();

    // Load this thread's 4 elements; compact relevant values into LDS.
    // Replace relevant k-values with -INF so they contribute exactly 0 to the
    // hinge sum -> the main loop below is branch-free / divergence-free.
    float myPred[PER_THREAD];
    #pragma unroll
    for (int i = 0; i < PER_THREAD; ++i) {
        const int idx = tid + i * BLOCK;       // coalesced
        const float p  = prow[idx];
        const float yy = yrow[idx];
        const bool rel = (yy == 1.0f);
        if (rel) {
            const int pos = atomicAdd(&relCount, 1);
            relVals[pos] = p;
        }
        myPred[i] = rel ? -INFINITY : p;
    }
    __syncthreads();

    const int nRel = relCount;

    float acc = 0.0f;
    for (int j = 0; j < nRel; ++j) {
        const float rv = relVals[j];           // same addr for all lanes: LDS broadcast
        #pragma unroll
        for (int i = 0; i < PER_THREAD; ++i) {
            acc += fmaxf(myPred[i] - rv, 0.0f);   // -INF - rv -> -INF -> 0
        }
    }

    // Block reduction: wave shuffle, then 4 wave sums via LDS.
    #pragma unroll
    for (int off = 32; off > 0; off >>= 1)
        acc += __shfl_down(acc, off, 64);
    const int wave = tid >> 6;
    const int lane = tid & 63;
    if (lane == 0) waveSums[wave] = acc;
    __syncthreads();
    if (tid == 0)
        partial[q] = waveSums[0] + waveSums[1] + waveSums[2] + waveSums[3];
}

// Reduce 64 per-query losses -> mean, single wave.
__global__ __launch_bounds__(64) void finalize_kernel(
    const float* __restrict__ partial,
    float* __restrict__ out)
{
    const int tid = threadIdx.x;
    float v = partial[tid];
    #pragma unroll
    for (int off = 32; off > 0; off >>= 1)
        v += __shfl_down(v, off, 64);
    if (tid == 0) out[0] = v * (1.0f / NUM_Q);
}

extern "C" void kernel_launch(void* const* d_in, const int* in_sizes, int n_in,
                              void* d_out, int out_size, void* d_ws, size_t ws_size,
                              hipStream_t stream) {
    const float* pred = (const float*)d_in[0];
    const float* y    = (const float*)d_in[1];
    float* out     = (float*)d_out;
    float* partial = (float*)d_ws;   // 64 floats of scratch

    per_query_loss_kernel<<<NUM_Q, BLOCK, 0, stream>>>(pred, y, partial);
    finalize_kernel<<<1, 64, 0, stream>>>(partial, out);
}